// Round 2
// baseline (1170.468 us; speedup 1.0000x reference)
//
#include <hip/hip_runtime.h>
#include <hip/hip_bf16.h>
#include <math.h>

// ---------------------------------------------------------------------------
// KAN-Conv CIFAR net on gfx950, round 2.
// Key change vs round 1: each thread computes GO output channels for one
// pooled pixel -> act records loaded once into registers, reused GO*4 times.
// Every layer: 65536 threads = 256 blocks = 1 block per image, so the per-
// block act working set (32-96 KB) stays L1/L2 resident.
// Weights pre-fused into 8-float records {bw, sw*sc (6), 0} once per call.
// ---------------------------------------------------------------------------

#define BATCH 256

__device__ __forceinline__ void bspline_basis(float x, float out[6]) {
    const float h = 2.0f / 3.0f;
    float g[10];
#pragma unroll
    for (int i = 0; i < 10; ++i) g[i] = (float)(i - 3) * h - 1.0f;
    float b[9];
#pragma unroll
    for (int i = 0; i < 9; ++i) b[i] = (x >= g[i] && x < g[i + 1]) ? 1.0f : 0.0f;
#pragma unroll
    for (int j = 1; j <= 3; ++j) {
#pragma unroll
        for (int i = 0; i + j < 9; ++i) {
            float left  = (x - g[i]) / (g[i + j] - g[i]);
            float right = (g[i + j + 1] - x) / (g[i + j + 1] - g[i + 1]);
            b[i] = left * b[i] + right * b[i + 1];
        }
    }
#pragma unroll
    for (int i = 0; i < 6; ++i) out[i] = b[i];
}

// Per-pixel activation record: [silu(x), b0..b5, 0] (8 floats, 32B aligned)
__global__ __launch_bounds__(256) void precompute_act(const float* __restrict__ x,
                                                      float* __restrict__ act, int n) {
    int i = blockIdx.x * blockDim.x + threadIdx.x;
    if (i >= n) return;
    float v = x[i];
    float silu = v / (1.0f + expf(-v));
    float bs[6];
    bspline_basis(v, bs);
    float4* o = (float4*)(act + (size_t)i * 8);
    o[0] = make_float4(silu, bs[0], bs[1], bs[2]);
    o[1] = make_float4(bs[3], bs[4], bs[5], 0.0f);
}

// Fuse {base_w, spline_w*scaler} into 8-float records for all three layers.
// Ranges: L1 = 8*27 = 216, L2 = 16*72 = 1152, L3 = 32*144 = 4608 records.
__global__ __launch_bounds__(256) void prep_weights(
        const float* __restrict__ bw1, const float* __restrict__ sw1, const float* __restrict__ sc1,
        const float* __restrict__ bw2, const float* __restrict__ sw2, const float* __restrict__ sc2,
        const float* __restrict__ bw3, const float* __restrict__ sw3, const float* __restrict__ sc3,
        float* __restrict__ w1, float* __restrict__ w2, float* __restrict__ w3) {
    int i = blockIdx.x * blockDim.x + threadIdx.x;
    const float *bw, *sw, *sc;
    float* dst;
    int j;
    if (i < 216)       { bw = bw1; sw = sw1; sc = sc1; dst = w1; j = i; }
    else if (i < 1368) { bw = bw2; sw = sw2; sc = sc2; dst = w2; j = i - 216; }
    else if (i < 5976) { bw = bw3; sw = sw3; sc = sc3; dst = w3; j = i - 1368; }
    else return;
    float s = sc[j];
    float4* o = (float4*)(dst + (size_t)j * 8);
    o[0] = make_float4(bw[j], sw[j * 6 + 0] * s, sw[j * 6 + 1] * s, sw[j * 6 + 2] * s);
    o[1] = make_float4(sw[j * 6 + 3] * s, sw[j * 6 + 4] * s, sw[j * 6 + 5] * s, 0.0f);
}

// Fused KAN conv3x3 (pad 1) + maxpool 2x2, GO output channels per thread.
// act:  [B, C, H, W, 8], wrec: [O, C*9, 8], out: [B, O, H/2, W/2]
// Thread order: sp fastest, then og, then b -> exactly 256 threads per image.
template <int C, int O, int GO, int H, int W>
__global__ __launch_bounds__(256) void kan_conv_pool(const float* __restrict__ act,
                                                     const float* __restrict__ wrec,
                                                     float* __restrict__ out) {
    constexpr int PH = H / 2, PW = W / 2, F = C * 9;
    constexpr int NOG = O / GO, SP = PH * PW;
    int idx = blockIdx.x * blockDim.x + threadIdx.x;
    if (idx >= BATCH * NOG * SP) return;
    int sp = idx % SP;
    int og = (idx / SP) % NOG;
    int b  = idx / (SP * NOG);
    int pw = sp % PW, ph = sp / PW;
    int o0 = og * GO;

    // Zero-padding record: silu(0)=0 but b_splines(0) is nonzero.
    float zrec[8];
    {
        float zb[6];
        bspline_basis(0.0f, zb);   // const-folds
        zrec[0] = 0.f;
#pragma unroll
        for (int i = 0; i < 6; ++i) zrec[1 + i] = zb[i];
        zrec[7] = 0.f;
    }

    float acc[GO][4];
#pragma unroll
    for (int g = 0; g < GO; ++g)
#pragma unroll
        for (int p = 0; p < 4; ++p) acc[g][p] = 0.f;

    const float* actb  = act + (size_t)b * C * H * W * 8;
    const float* wbase = wrec + (size_t)o0 * F * 8;

    for (int c = 0; c < C; ++c) {
        const float* actc = actb + (size_t)c * H * W * 8;
#pragma unroll
        for (int py = 0; py < 4; ++py) {
            int hh = 2 * ph - 1 + py;
#pragma unroll
            for (int px = 0; px < 4; ++px) {
                int ww = 2 * pw - 1 + px;
                float r0, r1, r2, r3, r4, r5, r6;
                if ((unsigned)hh < (unsigned)H && (unsigned)ww < (unsigned)W) {
                    const float4* ap = (const float4*)(actc + ((size_t)hh * W + ww) * 8);
                    float4 lo = ap[0], hi = ap[1];
                    r0 = lo.x; r1 = lo.y; r2 = lo.z; r3 = lo.w;
                    r4 = hi.x; r5 = hi.y; r6 = hi.z;
                } else {
                    r0 = zrec[0]; r1 = zrec[1]; r2 = zrec[2]; r3 = zrec[3];
                    r4 = zrec[4]; r5 = zrec[5]; r6 = zrec[6];
                }
#pragma unroll
                for (int dy = 0; dy < 2; ++dy) {
#pragma unroll
                    for (int dx = 0; dx < 2; ++dx) {
                        int ky = py - dy, kx = px - dx;
                        if (ky >= 0 && ky < 3 && kx >= 0 && kx < 3) {  // compile-time
                            int f = c * 9 + ky * 3 + kx;
#pragma unroll
                            for (int g = 0; g < GO; ++g) {
                                const float4* w4 = (const float4*)(wbase + ((size_t)g * F + f) * 8);
                                float4 wl = w4[0], wh = w4[1];
                                acc[g][dy * 2 + dx] +=
                                    r0 * wl.x + r1 * wl.y + r2 * wl.z + r3 * wl.w +
                                    r4 * wh.x + r5 * wh.y + r6 * wh.z;
                            }
                        }
                    }
                }
            }
        }
    }
#pragma unroll
    for (int g = 0; g < GO; ++g) {
        float m = fmaxf(fmaxf(acc[g][0], acc[g][1]), fmaxf(acc[g][2], acc[g][3]));
        out[(((size_t)b * O + o0 + g) * PH + ph) * PW + pw] = m;
    }
}

// out[n,o] = dot(h[n,:512], w[o,:512]) + bias[o]
__global__ __launch_bounds__(256) void linear_kernel(const float* __restrict__ h,
                                                     const float* __restrict__ w,
                                                     const float* __restrict__ bias,
                                                     float* __restrict__ out) {
    int idx = blockIdx.x * blockDim.x + threadIdx.x;
    if (idx >= BATCH * 100) return;
    int o = idx % 100;
    int n = idx / 100;
    const float4* hp = (const float4*)(h + (size_t)n * 512);
    const float4* wp = (const float4*)(w + (size_t)o * 512);
    float acc = 0.f;
#pragma unroll 4
    for (int i = 0; i < 128; ++i) {
        float4 a = hp[i];
        float4 b = wp[i];
        acc += a.x * b.x + a.y * b.y + a.z * b.z + a.w * b.w;
    }
    out[idx] = acc + bias[o];
}

extern "C" void kernel_launch(void* const* d_in, const int* in_sizes, int n_in,
                              void* d_out, int out_size, void* d_ws, size_t ws_size,
                              hipStream_t stream) {
    const float* x     = (const float*)d_in[0];
    const float* c1_bw = (const float*)d_in[1];
    const float* c1_sw = (const float*)d_in[2];
    const float* c1_sc = (const float*)d_in[3];
    const float* c2_bw = (const float*)d_in[4];
    const float* c2_sw = (const float*)d_in[5];
    const float* c2_sc = (const float*)d_in[6];
    const float* c3_bw = (const float*)d_in[7];
    const float* c3_sw = (const float*)d_in[8];
    const float* c3_sc = (const float*)d_in[9];
    const float* lin_w = (const float*)d_in[10];
    const float* lin_b = (const float*)d_in[11];
    float* out = (float*)d_out;

    float* ws = (float*)d_ws;
    // Workspace (floats): act reused across layers.
    float* act = ws;               // 6291456 (25.2 MB) = 786432 * 8
    float* h1  = ws + 6291456;     // 524288
    float* h2  = h1 + 524288;      // 131072
    float* h3  = h2 + 131072;      // 131072
    float* w1  = h3 + 131072;      // 216*8  = 1728
    float* w2  = w1 + 1728;        // 1152*8 = 9216
    float* w3  = w2 + 9216;        // 4608*8 = 36864
    // total = 7,125,696 floats = 28.5 MB

    const int BS = 256;

    // Fused weight records (independent of act chain; launch first).
    prep_weights<<<(5976 + BS - 1) / BS, BS, 0, stream>>>(
        c1_bw, c1_sw, c1_sc, c2_bw, c2_sw, c2_sc, c3_bw, c3_sw, c3_sc, w1, w2, w3);

    // ---- Layer 1: [256,3,32,32] -> [256,8,16,16], GO=8 -> 65536 threads
    {
        int n = BATCH * 3 * 32 * 32;
        precompute_act<<<(n + BS - 1) / BS, BS, 0, stream>>>(x, act, n);
        kan_conv_pool<3, 8, 8, 32, 32><<<256, BS, 0, stream>>>(act, w1, h1);
    }
    // ---- Layer 2: [256,8,16,16] -> [256,16,8,8], GO=4 -> 65536 threads
    {
        int n = BATCH * 8 * 16 * 16;
        precompute_act<<<(n + BS - 1) / BS, BS, 0, stream>>>(h1, act, n);
        kan_conv_pool<8, 16, 4, 16, 16><<<256, BS, 0, stream>>>(act, w2, h2);
    }
    // ---- Layer 3: [256,16,8,8] -> [256,32,4,4], GO=2 -> 65536 threads
    {
        int n = BATCH * 16 * 8 * 8;
        precompute_act<<<(n + BS - 1) / BS, BS, 0, stream>>>(h2, act, n);
        kan_conv_pool<16, 32, 2, 8, 8><<<256, BS, 0, stream>>>(act, w3, h3);
    }
    // ---- Final linear: [256,512] @ [100,512]^T + b -> [256,100]
    {
        int nt = BATCH * 100;
        linear_kernel<<<(nt + BS - 1) / BS, BS, 0, stream>>>(h3, lin_w, lin_b, out);
    }
}

// Round 4
// 329.849 us; speedup vs baseline: 3.5485x; 3.5485x over previous
//
#include <hip/hip_runtime.h>
#include <math.h>

// ---------------------------------------------------------------------------
// KAN-Conv CIFAR net on gfx950, round 4 (round-3 structure, L3 config fixed).
// Per conv block: stage zero-padded x tile -> compute [silu, b0..b5] records
// directly into LDS (even/odd column float4 planes, lo/hi split). Then
// f-outer loop: weight loads + LDS act reads + FMAs. No global act arrays.
// L3 uses GO=2, FS=2 so the f-split reduce buffer fits in the aliased tile.
// ---------------------------------------------------------------------------

#define BATCH 256

__device__ __forceinline__ void bspline_basis(float x, float bs[6]) {
    const float h = 2.0f / 3.0f;
    float g[10];
#pragma unroll
    for (int i = 0; i < 10; ++i) g[i] = (float)(i - 3) * h - 1.0f;
    float b[9];
#pragma unroll
    for (int i = 0; i < 9; ++i) b[i] = (x >= g[i] && x < g[i + 1]) ? 1.0f : 0.0f;
#pragma unroll
    for (int j = 1; j <= 3; ++j) {
        const float inv_d = 1.0f / ((float)j * h);
#pragma unroll
        for (int i = 0; i + j < 9; ++i) {
            float left  = (x - g[i]) * inv_d;
            float right = (g[i + j + 1] - x) * inv_d;
            b[i] = left * b[i] + right * b[i + 1];
        }
    }
#pragma unroll
    for (int i = 0; i < 6; ++i) bs[i] = b[i];
}

// Fuse {base_w, spline_w*scaler} into 8-float records for all three layers.
__global__ __launch_bounds__(256) void prep_weights(
        const float* __restrict__ bw1, const float* __restrict__ sw1, const float* __restrict__ sc1,
        const float* __restrict__ bw2, const float* __restrict__ sw2, const float* __restrict__ sc2,
        const float* __restrict__ bw3, const float* __restrict__ sw3, const float* __restrict__ sc3,
        float* __restrict__ w1, float* __restrict__ w2, float* __restrict__ w3) {
    int i = blockIdx.x * blockDim.x + threadIdx.x;
    const float *bw, *sw, *sc;
    float* dst;
    int j;
    if (i < 216)       { bw = bw1; sw = sw1; sc = sc1; dst = w1; j = i; }
    else if (i < 1368) { bw = bw2; sw = sw2; sc = sc2; dst = w2; j = i - 216; }
    else if (i < 5976) { bw = bw3; sw = sw3; sc = sc3; dst = w3; j = i - 1368; }
    else return;
    float s = sc[j];
    float4* o = (float4*)(dst + (size_t)j * 8);
    o[0] = make_float4(bw[j], sw[j * 6 + 0] * s, sw[j * 6 + 1] * s, sw[j * 6 + 2] * s);
    o[1] = make_float4(sw[j * 6 + 3] * s, sw[j * 6 + 4] * s, sw[j * 6 + 5] * s, 0.0f);
}

// Fused: basis precompute (LDS) + KAN conv3x3(pad1) + maxpool2.
// x: [B,C,H,W]; wrec: [O, C*9, 8] fused; out: [B,O,H/2,W/2].
// VS: vertical split of pooled rows across blocks (grid = BATCH*VS).
// FS: f-split (channel split) within block, LDS-reduced. NT threads.
template <int C, int O, int GO, int H, int W, int VS, int FS, int NT>
__global__ __launch_bounds__(NT, 2) void kan_conv_pool(
        const float* __restrict__ x,
        const float* __restrict__ wrec,
        float* __restrict__ out) {
    constexpr int PH = H / 2, PW = W / 2;
    constexpr int PR = PH / VS;            // pooled rows per block
    constexpr int R  = 2 * PR + 2;         // input tile rows (incl. halo)
    constexpr int TC = W + 2;              // input tile cols (incl. halo)
    constexpr int CP = TC / 2;             // cols per parity plane
    constexpr int F  = C * 9;
    constexpr int PPB = PR * PW;           // pooled pixels per block
    constexpr int NOG = O / GO;
    constexpr int CS = C / FS;             // channels per f-slice
    static_assert(NT == NOG * FS * PPB, "thread mapping");

    // Act planes: index ((c*R + row)*2 + parity)*CP + col/2.
    __shared__ float4 s_lo[C * R * 2 * CP];
    __shared__ float4 s_hi[C * R * 2 * CP];

    const int tid = threadIdx.x;
    const int bid = blockIdx.x;
    const int b = (VS > 1) ? (bid >> 1) : bid;
    const int v = (VS > 1) ? (bid & 1) : 0;
    const int r0 = v * (2 * PR) - 1;       // global row of tile row 0

    // ---- Stage: zero-padded x -> [silu, b0..b5] records in LDS
    const float* xb = x + (size_t)b * C * H * W;
    for (int i = tid; i < C * R * TC; i += NT) {
        int cc  = i / (R * TC);
        int rr  = (i / TC) % R;
        int col = i % TC;
        int gr = r0 + rr, gc = col - 1;
        float val = 0.0f;
        if ((unsigned)gr < (unsigned)H && (unsigned)gc < (unsigned)W)
            val = xb[(cc * H + gr) * W + gc];
        float silu = val / (1.0f + __expf(-val));
        float bs[6];
        bspline_basis(val, bs);
        int idx = ((cc * R + rr) * 2 + (col & 1)) * CP + (col >> 1);
        s_lo[idx] = make_float4(silu, bs[0], bs[1], bs[2]);
        s_hi[idx] = make_float4(bs[3], bs[4], bs[5], 0.0f);
    }
    __syncthreads();

    // ---- Thread mapping
    const int px = tid % PPB;
    const int fh = (tid / PPB) % FS;
    const int og = tid / (PPB * FS);
    const int phl = px / PW, pw = px % PW;
    const int o0 = og * GO;

    float acc[GO][4];
#pragma unroll
    for (int g = 0; g < GO; ++g)
#pragma unroll
        for (int p = 0; p < 4; ++p) acc[g][p] = 0.f;

    const int pbase = (2 * phl) * (2 * CP) + pw;
    const float* wbase = wrec + (size_t)o0 * F * 8;

    for (int cc = 0; cc < CS; ++cc) {
        const int c = fh * CS + cc;
        const float4* plo = s_lo + c * (R * 2 * CP);
        const float4* phi = s_hi + c * (R * 2 * CP);
#pragma unroll
        for (int ky = 0; ky < 3; ++ky) {
#pragma unroll
            for (int kx = 0; kx < 3; ++kx) {
                const int f = c * 9 + ky * 3 + kx;
                float4 wl[GO], wh[GO];
#pragma unroll
                for (int g = 0; g < GO; ++g) {
                    const float4* wp = (const float4*)(wbase + ((size_t)g * F + f) * 8);
                    wl[g] = wp[0];
                    wh[g] = wp[1];
                }
#pragma unroll
                for (int dy = 0; dy < 2; ++dy) {
#pragma unroll
                    for (int dx = 0; dx < 2; ++dx) {
                        const int s = dx + kx;
                        const int off = pbase + ((dy + ky) * 2 + (s & 1)) * CP + (s >> 1);
                        float4 lo = plo[off];
                        float4 hi = phi[off];
#pragma unroll
                        for (int g = 0; g < GO; ++g) {
                            acc[g][dy * 2 + dx] +=
                                lo.x * wl[g].x + lo.y * wl[g].y + lo.z * wl[g].z +
                                lo.w * wl[g].w + hi.x * wh[g].x + hi.y * wh[g].y +
                                hi.z * wh[g].z;
                        }
                    }
                }
            }
        }
    }

    // ---- f-split reduction (reduce buffer aliases the act tile)
    if (FS > 1) {
        float4* s_red = s_lo;
        static_assert(FS == 1 || NT * GO <= C * R * 2 * CP, "red fits");
        __syncthreads();                   // act reads done before overwrite
#pragma unroll
        for (int g = 0; g < GO; ++g)
            s_red[tid * GO + g] = make_float4(acc[g][0], acc[g][1], acc[g][2], acc[g][3]);
        __syncthreads();
        if (fh != 0) return;
#pragma unroll
        for (int fq = 1; fq < FS; ++fq)
#pragma unroll
            for (int g = 0; g < GO; ++g) {
                float4 t = s_red[(tid + fq * PPB) * GO + g];
                acc[g][0] += t.x; acc[g][1] += t.y; acc[g][2] += t.z; acc[g][3] += t.w;
            }
    }

    // ---- maxpool + store
    const int phg = v * PR + phl;
#pragma unroll
    for (int g = 0; g < GO; ++g) {
        float m = fmaxf(fmaxf(acc[g][0], acc[g][1]), fmaxf(acc[g][2], acc[g][3]));
        out[(((size_t)b * O + o0 + g) * PH + phg) * PW + pw] = m;
    }
}

// out[n,o] = dot(h[n,:512], w[o,:512]) + bias[o]
__global__ __launch_bounds__(256) void linear_kernel(const float* __restrict__ h,
                                                     const float* __restrict__ w,
                                                     const float* __restrict__ bias,
                                                     float* __restrict__ out) {
    int idx = blockIdx.x * blockDim.x + threadIdx.x;
    if (idx >= BATCH * 100) return;
    int o = idx % 100;
    int n = idx / 100;
    const float4* hp = (const float4*)(h + (size_t)n * 512);
    const float4* wp = (const float4*)(w + (size_t)o * 512);
    float acc = 0.f;
#pragma unroll 4
    for (int i = 0; i < 128; ++i) {
        float4 a = hp[i];
        float4 b = wp[i];
        acc += a.x * b.x + a.y * b.y + a.z * b.z + a.w * b.w;
    }
    out[idx] = acc + bias[o];
}

extern "C" void kernel_launch(void* const* d_in, const int* in_sizes, int n_in,
                              void* d_out, int out_size, void* d_ws, size_t ws_size,
                              hipStream_t stream) {
    const float* x     = (const float*)d_in[0];
    const float* c1_bw = (const float*)d_in[1];
    const float* c1_sw = (const float*)d_in[2];
    const float* c1_sc = (const float*)d_in[3];
    const float* c2_bw = (const float*)d_in[4];
    const float* c2_sw = (const float*)d_in[5];
    const float* c2_sc = (const float*)d_in[6];
    const float* c3_bw = (const float*)d_in[7];
    const float* c3_sw = (const float*)d_in[8];
    const float* c3_sc = (const float*)d_in[9];
    const float* lin_w = (const float*)d_in[10];
    const float* lin_b = (const float*)d_in[11];
    float* out = (float*)d_out;

    float* ws = (float*)d_ws;
    float* h1 = ws;                 // 256*8*16*16  = 524288
    float* h2 = h1 + 524288;        // 256*16*8*8   = 262144 (131072 used)
    float* h3 = h2 + 262144;        // 256*32*4*4   = 131072
    float* w1 = h3 + 131072;        // 216*8  = 1728
    float* w2 = w1 + 1728;          // 1152*8 = 9216
    float* w3 = w2 + 9216;          // 4608*8 = 36864
    // total 965312 floats = 3.9 MB

    // Fused weight records (independent; launch first).
    prep_weights<<<24, 256, 0, stream>>>(
        c1_bw, c1_sw, c1_sc, c2_bw, c2_sw, c2_sc, c3_bw, c3_sw, c3_sc, w1, w2, w3);

    // L1: [256,3,32,32] -> [256,8,16,16]; 512 blocks (b x row-half), GO=4.
    kan_conv_pool<3, 8, 4, 32, 32, 2, 1, 256><<<512, 256, 0, stream>>>(x, w1, h1);
    // L2: [256,8,16,16] -> [256,16,8,8]; 512 blocks, GO=2.
    kan_conv_pool<8, 16, 2, 16, 16, 2, 1, 256><<<512, 256, 0, stream>>>(h1, w2, h2);
    // L3: [256,16,8,8] -> [256,32,4,4]; 256 blocks, 512 thr, GO=2, f-split 2.
    kan_conv_pool<16, 32, 2, 8, 8, 1, 2, 512><<<256, 512, 0, stream>>>(h2, w3, h3);
    // Linear: [256,512] @ [100,512]^T + b.
    linear_kernel<<<100, 256, 0, stream>>>(h3, lin_w, lin_b, out);
}

// Round 5
// 169.384 us; speedup vs baseline: 6.9101x; 1.9473x over previous
//
#include <hip/hip_runtime.h>
#include <math.h>

// ---------------------------------------------------------------------------
// KAN-Conv CIFAR net on gfx950, round 5.
// vs round 4: (1) L1 weights staged in LDS (hi part as packed 12B triples) --
// kills the 216-in-flight-global-load spill (190MB fetch / 379MB write of
// scratch traffic observed in round 4); (2) unroll-1 on c and ky loops bounds
// the scheduler's load-hoisting window; (3) GO=4 on all layers amortizes act
// LDS reads over 4 output channels.
// ---------------------------------------------------------------------------

#define BATCH 256

struct W3 { float x, y, z; };   // packed 12-byte LDS record

__device__ __forceinline__ void bspline_basis(float x, float bs[6]) {
    const float h = 2.0f / 3.0f;
    float g[10];
#pragma unroll
    for (int i = 0; i < 10; ++i) g[i] = (float)(i - 3) * h - 1.0f;
    float b[9];
#pragma unroll
    for (int i = 0; i < 9; ++i) b[i] = (x >= g[i] && x < g[i + 1]) ? 1.0f : 0.0f;
#pragma unroll
    for (int j = 1; j <= 3; ++j) {
        const float inv_d = 1.0f / ((float)j * h);
#pragma unroll
        for (int i = 0; i + j < 9; ++i) {
            float left  = (x - g[i]) * inv_d;
            float right = (g[i + j + 1] - x) * inv_d;
            b[i] = left * b[i] + right * b[i + 1];
        }
    }
#pragma unroll
    for (int i = 0; i < 6; ++i) bs[i] = b[i];
}

// Fuse {base_w, spline_w*scaler} into 8-float records for all three layers.
__global__ __launch_bounds__(256) void prep_weights(
        const float* __restrict__ bw1, const float* __restrict__ sw1, const float* __restrict__ sc1,
        const float* __restrict__ bw2, const float* __restrict__ sw2, const float* __restrict__ sc2,
        const float* __restrict__ bw3, const float* __restrict__ sw3, const float* __restrict__ sc3,
        float* __restrict__ w1, float* __restrict__ w2, float* __restrict__ w3) {
    int i = blockIdx.x * blockDim.x + threadIdx.x;
    const float *bw, *sw, *sc;
    float* dst;
    int j;
    if (i < 216)       { bw = bw1; sw = sw1; sc = sc1; dst = w1; j = i; }
    else if (i < 1368) { bw = bw2; sw = sw2; sc = sc2; dst = w2; j = i - 216; }
    else if (i < 5976) { bw = bw3; sw = sw3; sc = sc3; dst = w3; j = i - 1368; }
    else return;
    float s = sc[j];
    float4* o = (float4*)(dst + (size_t)j * 8);
    o[0] = make_float4(bw[j], sw[j * 6 + 0] * s, sw[j * 6 + 1] * s, sw[j * 6 + 2] * s);
    o[1] = make_float4(sw[j * 6 + 3] * s, sw[j * 6 + 4] * s, sw[j * 6 + 5] * s, 0.0f);
}

// Fused: basis precompute (LDS) + KAN conv3x3(pad1) + maxpool2.
// x: [B,C,H,W]; wrec: [O, C*9, 8] fused; out: [B,O,H/2,W/2].
// VS: vertical split of pooled rows across blocks. FS: channel split within
// block (LDS-reduced). WLDS: stage weights in LDS (only fits for layer 1).
template <int C, int O, int GO, int H, int W, int VS, int FS, int NT, int WLDS>
__global__ __launch_bounds__(NT, 2) void kan_conv_pool(
        const float* __restrict__ x,
        const float* __restrict__ wrec,
        float* __restrict__ out) {
    constexpr int PH = H / 2, PW = W / 2;
    constexpr int PR = PH / VS;            // pooled rows per block
    constexpr int R  = 2 * PR + 2;         // input tile rows (incl. halo)
    constexpr int TC = W + 2;              // input tile cols (incl. halo)
    constexpr int CP = TC / 2;             // cols per parity plane
    constexpr int F  = C * 9;
    constexpr int PPB = PR * PW;           // pooled pixels per block
    constexpr int NOG = O / GO;
    constexpr int CS = C / FS;             // channels per f-slice
    static_assert(NT == NOG * FS * PPB, "thread mapping");

    // Act planes: index ((c*R + row)*2 + parity)*CP + col/2.
    __shared__ float4 s_lo[C * R * 2 * CP];
    __shared__ float4 s_hi[C * R * 2 * CP];
    constexpr int NWR = WLDS ? O * F : 1;
    __shared__ float4 s_wlo[NWR];
    __shared__ W3     s_whi[NWR];

    const int tid = threadIdx.x;
    const int bid = blockIdx.x;
    const int b = (VS > 1) ? (bid / VS) : bid;
    const int v = (VS > 1) ? (bid % VS) : 0;
    const int r0 = v * (2 * PR) - 1;       // global row of tile row 0

    // ---- Stage: zero-padded x -> [silu, b0..b5] records in LDS
    const float* xb = x + (size_t)b * C * H * W;
    for (int i = tid; i < C * R * TC; i += NT) {
        int cc  = i / (R * TC);
        int rr  = (i / TC) % R;
        int col = i % TC;
        int gr = r0 + rr, gc = col - 1;
        float val = 0.0f;
        if ((unsigned)gr < (unsigned)H && (unsigned)gc < (unsigned)W)
            val = xb[(cc * H + gr) * W + gc];
        float silu = val / (1.0f + __expf(-val));
        float bs[6];
        bspline_basis(val, bs);
        int idx = ((cc * R + rr) * 2 + (col & 1)) * CP + (col >> 1);
        s_lo[idx] = make_float4(silu, bs[0], bs[1], bs[2]);
        s_hi[idx] = make_float4(bs[3], bs[4], bs[5], 0.0f);
    }
    if (WLDS) {
        for (int j = tid; j < O * F; j += NT) {
            const float4* wp = (const float4*)(wrec + (size_t)j * 8);
            float4 lo = wp[0], hi = wp[1];
            s_wlo[j] = lo;
            W3 t; t.x = hi.x; t.y = hi.y; t.z = hi.z;
            s_whi[j] = t;
        }
    }
    __syncthreads();

    // ---- Thread mapping
    const int px = tid % PPB;
    const int fh = (tid / PPB) % FS;
    const int og = tid / (PPB * FS);
    const int phl = px / PW, pw = px % PW;
    const int o0 = og * GO;

    float acc[GO][4];
#pragma unroll
    for (int g = 0; g < GO; ++g)
#pragma unroll
        for (int p = 0; p < 4; ++p) acc[g][p] = 0.f;

    const int pbase = (2 * phl) * (2 * CP) + pw;
    const float* wbase = wrec + (size_t)o0 * F * 8;

#pragma unroll 1
    for (int cc = 0; cc < CS; ++cc) {
        const int c = fh * CS + cc;
        const float4* plo = s_lo + c * (R * 2 * CP);
        const float4* phi = s_hi + c * (R * 2 * CP);
#pragma unroll 1
        for (int ky = 0; ky < 3; ++ky) {
#pragma unroll
            for (int kx = 0; kx < 3; ++kx) {
                const int f = c * 9 + ky * 3 + kx;
                float4 wl[GO];
                float  whx[GO], why[GO], whz[GO];
#pragma unroll
                for (int g = 0; g < GO; ++g) {
                    if (WLDS) {
                        const int r = (o0 + g) * F + f;
                        wl[g] = s_wlo[r];
                        W3 t = s_whi[r];
                        whx[g] = t.x; why[g] = t.y; whz[g] = t.z;
                    } else {
                        const float4* wp = (const float4*)(wbase + ((size_t)g * F + f) * 8);
                        wl[g] = wp[0];
                        float4 h = wp[1];
                        whx[g] = h.x; why[g] = h.y; whz[g] = h.z;
                    }
                }
#pragma unroll
                for (int dy = 0; dy < 2; ++dy) {
#pragma unroll
                    for (int dx = 0; dx < 2; ++dx) {
                        const int s = dx + kx;
                        const int off = pbase + ((dy + ky) * 2 + (s & 1)) * CP + (s >> 1);
                        float4 lo = plo[off];
                        float4 hi = phi[off];
#pragma unroll
                        for (int g = 0; g < GO; ++g) {
                            acc[g][dy * 2 + dx] +=
                                lo.x * wl[g].x + lo.y * wl[g].y + lo.z * wl[g].z +
                                lo.w * wl[g].w + hi.x * whx[g] + hi.y * why[g] +
                                hi.z * whz[g];
                        }
                    }
                }
            }
        }
    }

    // ---- f-split reduction (reduce buffer aliases the act tile)
    if (FS > 1) {
        float4* s_red = s_lo;
        static_assert(FS == 1 || NT * GO <= C * R * 2 * CP, "red fits");
        __syncthreads();                   // act reads done before overwrite
#pragma unroll
        for (int g = 0; g < GO; ++g)
            s_red[tid * GO + g] = make_float4(acc[g][0], acc[g][1], acc[g][2], acc[g][3]);
        __syncthreads();
        if (fh != 0) return;
#pragma unroll
        for (int fq = 1; fq < FS; ++fq)
#pragma unroll
            for (int g = 0; g < GO; ++g) {
                float4 t = s_red[(tid + fq * PPB) * GO + g];
                acc[g][0] += t.x; acc[g][1] += t.y; acc[g][2] += t.z; acc[g][3] += t.w;
            }
    }

    // ---- maxpool + store
    const int phg = v * PR + phl;
#pragma unroll
    for (int g = 0; g < GO; ++g) {
        float m = fmaxf(fmaxf(acc[g][0], acc[g][1]), fmaxf(acc[g][2], acc[g][3]));
        out[(((size_t)b * O + o0 + g) * PH + phg) * PW + pw] = m;
    }
}

// out[n,o] = dot(h[n,:512], w[o,:512]) + bias[o]
__global__ __launch_bounds__(256) void linear_kernel(const float* __restrict__ h,
                                                     const float* __restrict__ w,
                                                     const float* __restrict__ bias,
                                                     float* __restrict__ out) {
    int idx = blockIdx.x * blockDim.x + threadIdx.x;
    if (idx >= BATCH * 100) return;
    int o = idx % 100;
    int n = idx / 100;
    const float4* hp = (const float4*)(h + (size_t)n * 512);
    const float4* wp = (const float4*)(w + (size_t)o * 512);
    float acc = 0.f;
#pragma unroll 4
    for (int i = 0; i < 128; ++i) {
        float4 a = hp[i];
        float4 b = wp[i];
        acc += a.x * b.x + a.y * b.y + a.z * b.z + a.w * b.w;
    }
    out[idx] = acc + bias[o];
}

extern "C" void kernel_launch(void* const* d_in, const int* in_sizes, int n_in,
                              void* d_out, int out_size, void* d_ws, size_t ws_size,
                              hipStream_t stream) {
    const float* x     = (const float*)d_in[0];
    const float* c1_bw = (const float*)d_in[1];
    const float* c1_sw = (const float*)d_in[2];
    const float* c1_sc = (const float*)d_in[3];
    const float* c2_bw = (const float*)d_in[4];
    const float* c2_sw = (const float*)d_in[5];
    const float* c2_sc = (const float*)d_in[6];
    const float* c3_bw = (const float*)d_in[7];
    const float* c3_sw = (const float*)d_in[8];
    const float* c3_sc = (const float*)d_in[9];
    const float* lin_w = (const float*)d_in[10];
    const float* lin_b = (const float*)d_in[11];
    float* out = (float*)d_out;

    float* ws = (float*)d_ws;
    float* h1 = ws;                 // 256*8*16*16  = 524288
    float* h2 = h1 + 524288;        // 256*16*8*8   = 262144
    float* h3 = h2 + 262144;        // 256*32*4*4   = 131072
    float* w1 = h3 + 131072;        // 216*8  = 1728
    float* w2 = w1 + 1728;          // 1152*8 = 9216
    float* w3 = w2 + 9216;          // 4608*8 = 36864
    // total 965312 floats = 3.9 MB

    // Fused weight records (independent; launch first).
    prep_weights<<<24, 256, 0, stream>>>(
        c1_bw, c1_sw, c1_sc, c2_bw, c2_sw, c2_sc, c3_bw, c3_sw, c3_sc, w1, w2, w3);

    // L1: [256,3,32,32] -> [256,8,16,16]; GO=4, weights in LDS. 512 blocks.
    kan_conv_pool<3, 8, 4, 32, 32, 2, 1, 256, 1><<<512, 256, 0, stream>>>(x, w1, h1);
    // L2: [256,8,16,16] -> [256,16,8,8]; GO=4, FS=2. 512 blocks.
    kan_conv_pool<8, 16, 4, 16, 16, 2, 2, 256, 0><<<512, 256, 0, stream>>>(h1, w2, h2);
    // L3: [256,16,8,8] -> [256,32,4,4]; GO=4, FS=2. 256 blocks.
    kan_conv_pool<16, 32, 4, 8, 8, 1, 2, 256, 0><<<256, 256, 0, stream>>>(h2, w3, h3);
    // Linear: [256,512] @ [100,512]^T + b.
    linear_kernel<<<100, 256, 0, stream>>>(h3, lin_w, lin_b, out);
}